// Round 7
// baseline (243.747 us; speedup 1.0000x reference)
//
#include <hip/hip_runtime.h>
#include <math.h>

// x: (16, 512, 512, 8) float32 NHWC. float4 "granule" = 4 channels.
// Image row = 1024 granules. Block stages a (HPT+2) x 260-granule tile of x
// into LDS exactly once (OOB -> -inf), then serves all 9-point windows from
// LDS. vs round 4 (same idea, 111 us): HPT 8 -> 4 cuts LDS 42 KB -> 25 KB,
// lifting occupancy 3 -> 6 blocks/CU (12 -> 24 waves) and staggering the
// per-block barrier phases. Theory: the ~82 us plateau of rounds 1-6 is
// L2 pending-request (MSHR) occupancy from duplicate line requests; this
// structure requests each line once. NT stores keep 'out' from evicting
// x's halo rows in L2/L3.

constexpr int Hdim = 512;
constexpr int Wdim = 512;
constexpr int HPT  = 4;
constexpr int ROWS = HPT + 2;         // 6
constexpr int GPB  = 256;             // granules owned per block
constexpr int HALO = 2;               // +/-1 pixel = 2 granules
constexpr int LW   = GPB + 2 * HALO;  // 260
constexpr int ROWG = Wdim * 2;        // 1024 granules per image row

typedef float v4f __attribute__((ext_vector_type(4)));

__device__ __forceinline__ v4f f4max(v4f a, v4f b) {
    v4f r;
    r.x = fmaxf(a.x, b.x); r.y = fmaxf(a.y, b.y);
    r.z = fmaxf(a.z, b.z); r.w = fmaxf(a.w, b.w);
    return r;
}
__device__ __forceinline__ v4f f4sel(bool ok, v4f v, v4f e) {
    v4f r;
    r.x = ok ? v.x : e.x; r.y = ok ? v.y : e.y;
    r.z = ok ? v.z : e.z; r.w = ok ? v.w : e.w;
    return r;
}

__global__ __launch_bounds__(256) void nms_kernel(
    const v4f* __restrict__ x,
    const unsigned char* __restrict__ mask_bytes,
    v4f* __restrict__ out)
{
    __shared__ v4f lds[ROWS][LW];     // 6 * 260 * 16 = 24960 B -> 6 blocks/CU

    // ---- Decode 3x3 boolean mask robustly (int32 vs 1-byte bool layout).
    const int* mi = (const int*)mask_bytes;
    bool intlay = true;
    #pragma unroll
    for (int i = 0; i < 9; ++i) { int v = mi[i]; intlay = intlay && (v == 0 || v == 1); }
    bool m[9];
    #pragma unroll
    for (int i = 0; i < 9; ++i) m[i] = intlay ? (mi[i] != 0) : (mask_bytes[i] != 0);

    const v4f NEG = { -INFINITY, -INFINITY, -INFINITY, -INFINITY };

    int t   = threadIdx.x;
    int bid = blockIdx.x;
    int gb  = bid & 3;            // 4 blocks span one image row
    int hg  = (bid >> 2) & 127;   // 128 h-strips of 4 rows
    int n   = bid >> 9;           // 16 images
    int g0  = gb * GPB;
    int h0  = hg * HPT;

    // ---- Stage ROWS x LW granules into LDS once; -inf outside the image.
    #pragma unroll
    for (int r = 0; r < ROWS; ++r) {
        int hr  = h0 - 1 + r;
        int hrc = hr < 0 ? 0 : (hr > Hdim - 1 ? Hdim - 1 : hr);
        bool hok = (hr == hrc);                        // block-uniform
        long rowbase = ((long)(n * Hdim + hrc)) * ROWG;
        {
            int gc  = g0 - HALO + t;
            int gcc = gc < 0 ? 0 : (gc > ROWG - 1 ? ROWG - 1 : gc);
            v4f v = x[rowbase + gcc];
            lds[r][t] = f4sel(hok && (gc == gcc), v, NEG);
        }
        if (t < 2 * HALO) {                            // 4 halo granules/row
            int c   = GPB + t;
            int gc  = g0 - HALO + c;
            int gcc = gc < 0 ? 0 : (gc > ROWG - 1 ? ROWG - 1 : gc);
            v4f v = x[rowbase + gcc];
            lds[r][c] = f4sel(hok && (gc == gcc), v, NEG);
        }
    }
    __syncthreads();

    // ---- Rolling 3-row register window served from LDS.
    v4f A0 = lds[0][t], B0 = lds[0][t + 2], C0 = lds[0][t + 4];
    v4f A1 = lds[1][t], B1 = lds[1][t + 2], C1 = lds[1][t + 4];

    long obase = ((long)(n * Hdim + h0)) * ROWG + g0 + t;

    #pragma unroll
    for (int s = 0; s < HPT; ++s) {
        v4f A2 = lds[s + 2][t], B2 = lds[s + 2][t + 2], C2 = lds[s + 2][t + 4];

        v4f va = NEG, vb = NEG, vc = NEG;
        if (m[0]) va = f4max(va, A0);
        if (m[3]) va = f4max(va, A1);
        if (m[6]) va = f4max(va, A2);
        if (m[1]) vb = f4max(vb, B0);
        if (m[4]) vb = f4max(vb, B1);
        if (m[7]) vb = f4max(vb, B2);
        if (m[2]) vc = f4max(vc, C0);
        if (m[5]) vc = f4max(vc, C1);
        if (m[8]) vc = f4max(vc, C2);

        v4f mm = f4max(f4max(va, vb), vc);
        v4f ctr = B1;
        v4f o;
        o.x = (ctr.x > mm.x) ? ctr.x : 0.0f;
        o.y = (ctr.y > mm.y) ? ctr.y : 0.0f;
        o.z = (ctr.z > mm.z) ? ctr.z : 0.0f;
        o.w = (ctr.w > mm.w) ? ctr.w : 0.0f;
        __builtin_nontemporal_store(o, &out[obase + (long)s * ROWG]);

        A0 = A1; A1 = A2;
        B0 = B1; B1 = B2;
        C0 = C1; C1 = C2;
    }
}

extern "C" void kernel_launch(void* const* d_in, const int* in_sizes, int n_in,
                              void* d_out, int out_size, void* d_ws, size_t ws_size,
                              hipStream_t stream) {
    const v4f* x = (const v4f*)d_in[0];
    const unsigned char* mask = (const unsigned char*)d_in[1];
    v4f* out = (v4f*)d_out;

    int grid = 16 * (Hdim / HPT) * (ROWG / GPB);  // 16*128*4 = 8192 blocks
    nms_kernel<<<grid, 256, 0, stream>>>(x, mask, out);
}

// Round 8
// 234.979 us; speedup vs baseline: 1.0373x; 1.0373x over previous
//
#include <hip/hip_runtime.h>
#include <math.h>
#include <stdint.h>

// x: (16, 512, 512, 8) float32 NHWC. float4 granule idx:
//   idx = ((n*512 + h)*512 + w)*2 + c4
// One output granule per thread (max occupancy). vs round 5/6: the 9
// stencil loads are issued as inline-asm global_load_dwordx4 with distinct
// "=v" float4 destinations -> the register allocator CANNOT collapse the
// window (rounds 1-7 all showed VGPR 12-40, i.e. 2-3 loads in flight,
// 3-4 serial ~1300cyc latency rounds per output = the ~82us plateau).
// One s_waitcnt vmcnt(0) after all 9 issue: one latency round per output.

constexpr int Hdim = 512;
constexpr int Wdim = 512;
constexpr int ROWG = Wdim * 2;   // granules per image row

typedef float v4f __attribute__((ext_vector_type(4)));

__device__ __forceinline__ v4f f4max(v4f a, v4f b) {
    v4f r;
    r.x = fmaxf(a.x, b.x); r.y = fmaxf(a.y, b.y);
    r.z = fmaxf(a.z, b.z); r.w = fmaxf(a.w, b.w);
    return r;
}

__device__ __forceinline__ void gload(v4f& dst, const v4f* p) {
    asm volatile("global_load_dwordx4 %0, %1, off"
                 : "=v"(dst)
                 : "v"((uint64_t)(uintptr_t)p));
}

__global__ __launch_bounds__(256) void nms_kernel(
    const v4f* __restrict__ x,
    const unsigned char* __restrict__ mask_bytes,
    v4f* __restrict__ out)
{
    // ---- Decode 3x3 boolean mask robustly (int32 vs 1-byte bool layout).
    // Uniform pointer -> scalar loads (lgkmcnt), no vmcnt interference.
    const int* mi = (const int*)mask_bytes;
    bool intlay = true;
    #pragma unroll
    for (int i = 0; i < 9; ++i) { int v = mi[i]; intlay = intlay && (v == 0 || v == 1); }
    bool m[9];
    #pragma unroll
    for (int i = 0; i < 9; ++i) m[i] = intlay ? (mi[i] != 0) : (mask_bytes[i] != 0);

    int idx = blockIdx.x * blockDim.x + threadIdx.x;  // grid covers all granules

    int w = (idx >> 1) & (Wdim - 1);
    int h = (idx >> 10) & (Hdim - 1);

    bool hup = (h > 0), hdn = (h < Hdim - 1);
    bool wlf = (w > 0), wrt = (w < Wdim - 1);
    int oN = hup ? -ROWG : 0;
    int oS = hdn ?  ROWG : 0;
    int oW = wlf ? -2 : 0;
    int oE = wrt ?  2 : 0;

    const v4f* base = x + idx;

    // ---- 9 loads, forced back-to-back, distinct live destinations.
    v4f vNW, vN, vNE, vW, vC, vE, vSW, vS, vSE;
    gload(vNW, base + oN + oW);
    gload(vN , base + oN);
    gload(vNE, base + oN + oE);
    gload(vW , base + oW);
    gload(vC , base);
    gload(vE , base + oE);
    gload(vSW, base + oS + oW);
    gload(vS , base + oS);
    gload(vSE, base + oS + oE);
    asm volatile("s_waitcnt vmcnt(0)" ::: "memory");

    bool k0 = m[0] && hup && wlf;
    bool k1 = m[1] && hup;
    bool k2 = m[2] && hup && wrt;
    bool k3 = m[3] && wlf;
    bool k4 = m[4];
    bool k5 = m[5] && wrt;
    bool k6 = m[6] && hdn && wlf;
    bool k7 = m[7] && hdn;
    bool k8 = m[8] && hdn && wrt;

    const v4f NEG = { -INFINITY, -INFINITY, -INFINITY, -INFINITY };
    v4f mm = NEG;
    if (k0) mm = f4max(mm, vNW);
    if (k1) mm = f4max(mm, vN);
    if (k2) mm = f4max(mm, vNE);
    if (k3) mm = f4max(mm, vW);
    if (k4) mm = f4max(mm, vC);
    if (k5) mm = f4max(mm, vE);
    if (k6) mm = f4max(mm, vSW);
    if (k7) mm = f4max(mm, vS);
    if (k8) mm = f4max(mm, vSE);

    v4f o;
    o.x = (vC.x > mm.x) ? vC.x : 0.0f;
    o.y = (vC.y > mm.y) ? vC.y : 0.0f;
    o.z = (vC.z > mm.z) ? vC.z : 0.0f;
    o.w = (vC.w > mm.w) ? vC.w : 0.0f;
    out[idx] = o;
}

extern "C" void kernel_launch(void* const* d_in, const int* in_sizes, int n_in,
                              void* d_out, int out_size, void* d_ws, size_t ws_size,
                              hipStream_t stream) {
    const v4f* x = (const v4f*)d_in[0];
    const unsigned char* mask = (const unsigned char*)d_in[1];
    v4f* out = (v4f*)d_out;

    int total4 = out_size / 4;      // 8,388,608 = 32768 * 256 exactly
    int block = 256;
    int grid = total4 / block;      // 32768 blocks, no remainder
    nms_kernel<<<grid, block, 0, stream>>>(x, mask, out);
}